// Round 1
// baseline (16.479 us; speedup 1.0000x reference)
//
#include <hip/hip_runtime.h>

// Attentionlayer: B=4, T=12, N=1024, F_IN=64, F_OUT=64.
//
// Key identity: softmax(att, axis=3) summed over axis=3 is exactly 1 for every
// (b,t,n) row (softmax normalizes over that axis; even fully-masked rows give a
// uniform distribution summing to 1). Hence
//   res = leaky_relu(h * 1) = leaky_relu(x @ W)
// The adjacency / attention-score path contributes nothing to the output.
// Numerical deviation vs the float32 np reference is ~1e-5, threshold is 1.48e-1.

constexpr int K_IN  = 64;             // F_IN
constexpr int C_OUT = 64;             // F_OUT
constexpr int ROWS  = 4 * 12 * 1024;  // B*T*N = 49152

// Block = 256 threads = 4 waves. Each wave handles 64 rows x a 16-column slice
// of W (wave-uniform slice -> W loads become scalar s_load, FMAs read SGPRs).
__global__ __launch_bounds__(256) void gat_fused_kernel(
    const float* __restrict__ x, const float* __restrict__ W,
    float* __restrict__ out) {
  const int lane = threadIdx.x & 63;
  const int wid  = threadIdx.x >> 6;  // 0..3
  const int c0   = __builtin_amdgcn_readfirstlane(wid << 4);  // SGPR col base
  const int row  = (blockIdx.x << 6) + lane;

  // Load this lane's x row (64 floats) into registers, 16B at a time.
  const float* xrow = x + (size_t)row * K_IN;
  float xk[K_IN];
#pragma unroll
  for (int i = 0; i < K_IN / 4; ++i) {
    float4 v = reinterpret_cast<const float4*>(xrow)[i];
    xk[4 * i + 0] = v.x;
    xk[4 * i + 1] = v.y;
    xk[4 * i + 2] = v.z;
    xk[4 * i + 3] = v.w;
  }

  float acc[16];
#pragma unroll
  for (int j = 0; j < 16; ++j) acc[j] = 0.f;

  // h[row][c0+j] = sum_k x[row][k] * W[k][c0+j]
  // W address is wave-uniform (c0 in SGPR, k/j compile-time) -> scalar loads.
#pragma unroll
  for (int k = 0; k < K_IN; ++k) {
    const float* wrow = W + k * C_OUT + c0;
#pragma unroll
    for (int j = 0; j < 16; ++j)
      acc[j] = fmaf(xk[k], wrow[j], acc[j]);
  }

  // leaky_relu (negative_slope = 0.01, jax.nn.leaky_relu default) + store.
  float* orow = out + (size_t)row * C_OUT + c0;
#pragma unroll
  for (int q = 0; q < 4; ++q) {
    float a0 = acc[4 * q + 0], a1 = acc[4 * q + 1];
    float a2 = acc[4 * q + 2], a3 = acc[4 * q + 3];
    float4 v;
    v.x = a0 > 0.f ? a0 : 0.01f * a0;
    v.y = a1 > 0.f ? a1 : 0.01f * a1;
    v.z = a2 > 0.f ? a2 : 0.01f * a2;
    v.w = a3 > 0.f ? a3 : 0.01f * a3;
    reinterpret_cast<float4*>(orow)[q] = v;
  }
}

extern "C" void kernel_launch(void* const* d_in, const int* in_sizes, int n_in,
                              void* d_out, int out_size, void* d_ws, size_t ws_size,
                              hipStream_t stream) {
  // setup_inputs order: x, adj, W, a. Only x and W matter (see identity above).
  const float* x = (const float*)d_in[0];
  const float* W = (const float*)d_in[2];
  float* out     = (float*)d_out;

  dim3 grid(ROWS / 64);  // 768 blocks
  dim3 block(256);
  gat_fused_kernel<<<grid, block, 0, stream>>>(x, W, out);
}